// Round 2
// baseline (158.141 us; speedup 1.0000x reference)
//
#include <hip/hip_runtime.h>
#include <hip/hip_bf16.h>
#include <math.h>

// HungarianMatcher cost-matrix kernel.
// Shapes (from reference setup): bs=8, Q=1024, T=512, npt=2, num_classes=2.
//   pred_logits [bs,Q,2]      -> 16384 f32
//   pred_boxes  [bs,Q,4]      -> 32768 f32
//   tgt_pts     [bs,T,2,2]    -> 16384 f32  (flat: [bs*T, 4])
//   tgt_labels  [bs,T] int32  -> 4096 i32
// Output C [bs, Q, bs*T] = [8, 1024, 4096] f32 (134 MB) — write-BW bound.
//
// C[i,j] = sum_k |boxes[i][k] - tgt[j][k]|  -  sigmoid(logits[i])[labels[j]]
// (cost_bbox scale = 4.0 / 4 = 1.0; COST_CLASS = COST_BBOX = 1.0)

#define COLS4 1024   // 4096 cols / 4 per float4
#define ITERS 4      // 1024 float4-cols / 256 threads

__global__ __launch_bounds__(256) void matcher_cost_kernel(
    const float* __restrict__ logits,   // [rows, 2]
    const float* __restrict__ boxes,    // [rows, 4]
    const float* __restrict__ tgt,      // [4096, 4]
    const int*   __restrict__ ids,      // [4096]
    float* __restrict__ out)            // [rows, 4096]
{
    const int row = blockIdx.x;
    const int tid = threadIdx.x;

    // Per-row data: one float4 box, two sigmoid probabilities.
    const float4 bx = reinterpret_cast<const float4*>(boxes)[row];
    const float l0 = logits[row * 2 + 0];
    const float l1 = logits[row * 2 + 1];
    const float p0 = 1.0f / (1.0f + __expf(-l0));
    const float p1 = 1.0f / (1.0f + __expf(-l1));

    float* __restrict__ orow = out + (size_t)row * (COLS4 * 4);
    const float4* __restrict__ tgt4 = reinterpret_cast<const float4*>(tgt);
    const int4*   __restrict__ ids4 = reinterpret_cast<const int4*>(ids);

#pragma unroll
    for (int it = 0; it < ITERS; ++it) {
        const int jc = tid + it * 256;       // float4 column index, 0..1023
        const int jbase = jc * 4;            // scalar column index

        const int4 id4 = ids4[jc];

        float4 r;
        {
            const float4 t = tgt4[jbase + 0];
            const float l1c = fabsf(bx.x - t.x) + fabsf(bx.y - t.y) +
                              fabsf(bx.z - t.z) + fabsf(bx.w - t.w);
            r.x = l1c - (id4.x ? p1 : p0);
        }
        {
            const float4 t = tgt4[jbase + 1];
            const float l1c = fabsf(bx.x - t.x) + fabsf(bx.y - t.y) +
                              fabsf(bx.z - t.z) + fabsf(bx.w - t.w);
            r.y = l1c - (id4.y ? p1 : p0);
        }
        {
            const float4 t = tgt4[jbase + 2];
            const float l1c = fabsf(bx.x - t.x) + fabsf(bx.y - t.y) +
                              fabsf(bx.z - t.z) + fabsf(bx.w - t.w);
            r.z = l1c - (id4.z ? p1 : p0);
        }
        {
            const float4 t = tgt4[jbase + 3];
            const float l1c = fabsf(bx.x - t.x) + fabsf(bx.y - t.y) +
                              fabsf(bx.z - t.z) + fabsf(bx.w - t.w);
            r.w = l1c - (id4.w ? p1 : p0);
        }

        reinterpret_cast<float4*>(orow)[jc] = r;
    }
}

extern "C" void kernel_launch(void* const* d_in, const int* in_sizes, int n_in,
                              void* d_out, int out_size, void* d_ws, size_t ws_size,
                              hipStream_t stream) {
    const float* logits = (const float*)d_in[0];   // pred_logits  [8,1024,2]
    const float* boxes  = (const float*)d_in[1];   // pred_boxes   [8,1024,4]
    const float* tgt    = (const float*)d_in[2];   // tgt_pts      [8,512,2,2]
    const int*   ids    = (const int*)d_in[3];     // tgt_labels   [8,512]
    float* out = (float*)d_out;

    const int rows = in_sizes[1] / 4;              // bs*Q = 8192
    // cols = in_sizes[3] = 4096, baked into kernel constants (COLS4*4)

    matcher_cost_kernel<<<rows, 256, 0, stream>>>(logits, boxes, tgt, ids, out);
}

// Round 5
// 144.084 us; speedup vs baseline: 1.0976x; 1.0976x over previous
//
#include <hip/hip_runtime.h>
#include <hip/hip_bf16.h>
#include <math.h>

// HungarianMatcher cost-matrix kernel, round 3: 4-rows-per-block tiling.
// Shapes: bs=8, Q=1024, T=512, npt=2, C=2.
//   out[row, j] = sum_k |boxes[row][k] - tgt[j][k]| - sigmoid(logits[row])[ids[j]]
// out is [8192, 4096] f32 = 134 MB -> write-BW bound (fills prove 6.6 TB/s achievable).
//
// Round-2 evidence: 1-row-per-block ran ~77 us (1.7 TB/s). Cause: 80 B of
// column loads per 64 B stored, 655 MB aggregate L2 read traffic (column
// table re-read by every block). Fix: reuse each column load across 4 rows.

#define COLS   4096
#define COLS4  1024        // float4 columns
#define RPB    4           // rows per block
#define ITERS  4           // 1024 col4 / 256 threads

__device__ __forceinline__ float l1d(const float4 a, const float4 b) {
    return fabsf(a.x - b.x) + fabsf(a.y - b.y) +
           fabsf(a.z - b.z) + fabsf(a.w - b.w);
}

__global__ __launch_bounds__(256) void matcher_cost_kernel(
    const float* __restrict__ logits,   // [rows, 2]
    const float* __restrict__ boxes,    // [rows, 4]
    const float* __restrict__ tgt,      // [4096, 4]
    const int*   __restrict__ ids,      // [4096]
    float* __restrict__ out)            // [rows, 4096]
{
    const int tid = threadIdx.x;
    const int r0  = blockIdx.x * RPB;

    // Per-row constants: box float4, nb = -p0, dp = p0 - p1.
    //   cost = l1 - (id ? p1 : p0) = l1 + nb + sel*dp,  sel = (id != 0)
    float4 bx[RPB];
    float  nb[RPB], dp[RPB];
#pragma unroll
    for (int r = 0; r < RPB; ++r) {
        const int row = r0 + r;
        bx[r] = reinterpret_cast<const float4*>(boxes)[row];
        const float p0 = 1.0f / (1.0f + __expf(-logits[row * 2 + 0]));
        const float p1 = 1.0f / (1.0f + __expf(-logits[row * 2 + 1]));
        nb[r] = -p0;
        dp[r] = p0 - p1;
    }

    const float4* __restrict__ tgt4 = reinterpret_cast<const float4*>(tgt);
    const int4*   __restrict__ ids4 = reinterpret_cast<const int4*>(ids);
    float4* __restrict__ out4 = reinterpret_cast<float4*>(out);

#pragma unroll
    for (int it = 0; it < ITERS; ++it) {
        const int jc = tid + it * 256;       // float4 column index
        const int jb = jc * 4;

        const int4 id4 = ids4[jc];
        const float sx = id4.x ? 1.0f : 0.0f;
        const float sy = id4.y ? 1.0f : 0.0f;
        const float sz = id4.z ? 1.0f : 0.0f;
        const float sw = id4.w ? 1.0f : 0.0f;

        const float4 t0 = tgt4[jb + 0];
        const float4 t1 = tgt4[jb + 1];
        const float4 t2 = tgt4[jb + 2];
        const float4 t3 = tgt4[jb + 3];

#pragma unroll
        for (int r = 0; r < RPB; ++r) {
            float4 res;
            res.x = fmaf(sx, dp[r], l1d(bx[r], t0) + nb[r]);
            res.y = fmaf(sy, dp[r], l1d(bx[r], t1) + nb[r]);
            res.z = fmaf(sz, dp[r], l1d(bx[r], t2) + nb[r]);
            res.w = fmaf(sw, dp[r], l1d(bx[r], t3) + nb[r]);
            out4[(size_t)(r0 + r) * COLS4 + jc] = res;
        }
    }
}

extern "C" void kernel_launch(void* const* d_in, const int* in_sizes, int n_in,
                              void* d_out, int out_size, void* d_ws, size_t ws_size,
                              hipStream_t stream) {
    const float* logits = (const float*)d_in[0];   // pred_logits  [8,1024,2]
    const float* boxes  = (const float*)d_in[1];   // pred_boxes   [8,1024,4]
    const float* tgt    = (const float*)d_in[2];   // tgt_pts      [8,512,2,2]
    const int*   ids    = (const int*)d_in[3];     // tgt_labels   [8,512]
    float* out = (float*)d_out;

    const int rows = in_sizes[1] / 4;              // bs*Q = 8192
    matcher_cost_kernel<<<rows / RPB, 256, 0, stream>>>(logits, boxes, tgt, ids, out);
}